// Round 2
// baseline (513.510 us; speedup 1.0000x reference)
//
#include <hip/hip_runtime.h>

// ============================================================================
// Attention_14362370637857 on MI355X (gfx950).
// B=2, S=2048, D_MODEL=2048, NH=32, NKV=8 (GQA rep=4), DH=64.
//
// Input dtype is runtime-detected (bf16 vs f32) because the harness contract
// is ambiguous: detect_kernel sniffs residual; convert_kernel canonicalizes
// all inputs to bf16 in ws; the final GEMM writes d_out as bf16 or f32 per
// the same flag. All compute is bf16 MFMA with f32 accumulation.
//
// Pipeline:
//   1) detect_kernel   : residual-as-bf16 sanity scan -> flag (1 = f32 inputs)
//   2) convert_kernel  : residual,W_Q,W_K,W_V -> canonical bf16 in ws
//   3) qkv_gemm_kernel : R[4096,2048] x W^T -> q (in d_out), k, v
//   4) attn_kernel     : causal flash attention -> abuf
//   5) transpose_kernel: W_O -> W_O^T (flag-aware read)
//   6) out_gemm_kernel : abuf x W_O^T -> d_out (bf16 or f32 per flag)
// ============================================================================

typedef __attribute__((ext_vector_type(8))) short short8;  // 8 bf16 = 4 VGPRs
typedef __attribute__((ext_vector_type(4))) float f32x4;   // MFMA 16x16 C/D

__device__ __forceinline__ short f2bs(float f) {  // f32 -> bf16 bits, RNE
  unsigned u = __float_as_uint(f);
  u = (u + 0x7fffu + ((u >> 16) & 1u)) >> 16;
  return (short)u;
}
__device__ __forceinline__ float bs2f(short s) {  // bf16 bits -> f32
  return __uint_as_float(((unsigned)(unsigned short)s) << 16);
}

// async global->LDS, 16B per lane; lane l lands at base + l*16 (wave-uniform
// base, lane-order-contiguous LDS layout required).
__device__ __forceinline__ void async_ld16(const void* g, void* l) {
  __builtin_amdgcn_global_load_lds((__attribute__((address_space(1))) void*)(g),
                                   (__attribute__((address_space(3))) void*)(l),
                                   16, 0, 0);
}

// ----------------------------------------------------------------------------
// Dtype sniffing: bf16 N(0,1) data has |x| < ~6 everywhere; f32 data read as
// shorts has mantissa halves with uniform exponents -> |x| > 100 guaranteed
// among 4096 samples. flag = 1 means "inputs are f32".
// ----------------------------------------------------------------------------
__global__ __launch_bounds__(256) void detect_kernel(const short* __restrict__ r,
                                                     int* __restrict__ flag) {
  __shared__ int bad;
  if (threadIdx.x == 0) bad = 0;
  __syncthreads();
  int mybad = 0;
#pragma unroll
  for (int i = 0; i < 16; ++i) {
    float x = bs2f(r[threadIdx.x + i * 256]);
    if (!(fabsf(x) < 100.0f)) mybad = 1;  // catches huge / tiny-NaN patterns
  }
  if (mybad) atomicOr(&bad, 1);
  __syncthreads();
  if (threadIdx.x == 0) *flag = bad;
}

// ----------------------------------------------------------------------------
// Canonicalize residual, W_Q, W_K, W_V to bf16. 8 elements/thread.
// Chunk counts (8-elem units): 1048576 + 524288 + 131072 + 131072 = 1835008
// = 7168 blocks x 256 exactly.
// ----------------------------------------------------------------------------
__global__ __launch_bounds__(256) void convert_kernel(
    const void* __restrict__ s0, const void* __restrict__ s1,
    const void* __restrict__ s2, const void* __restrict__ s3,
    short* __restrict__ d0, short* __restrict__ d1, short* __restrict__ d2,
    short* __restrict__ d3, const int* __restrict__ flag) {
  long off = (long)blockIdx.x * 256 + threadIdx.x;
  const void* src;
  short* dst;
  if (off < 1048576) {
    src = s0; dst = d0;
  } else if ((off -= 1048576) < 524288) {
    src = s1; dst = d1;
  } else if ((off -= 524288) < 131072) {
    src = s2; dst = d2;
  } else {
    off -= 131072; src = s3; dst = d3;
  }
  const long e = off * 8;
  short8 v;
  if (*flag) {
    const float* f = (const float*)src + e;
    const f32x4 a = *(const f32x4*)(f);
    const f32x4 b = *(const f32x4*)(f + 4);
#pragma unroll
    for (int j = 0; j < 4; ++j) {
      v[j] = f2bs(a[j]);
      v[4 + j] = f2bs(b[j]);
    }
  } else {
    v = *(const short8*)((const short*)src + e);
  }
  *(short8*)(dst + e) = v;
}

// ----------------------------------------------------------------------------
// C[M,N] = A[M,K] * B[N,K]^T (row-major bf16), 128x128 tile, BK=32,
// 256 threads = 4 waves, each wave a 64x64 quadrant (4x4 MFMA tiles).
// outF32 selects the C element type (uniform).
// ----------------------------------------------------------------------------
__device__ __forceinline__ void gemm128(const short* __restrict__ A, int lda,
                                        const short* __restrict__ B, int ldb,
                                        void* __restrict__ C, int ldc,
                                        int rowBase, int colBase, int K,
                                        short* As, short* Bs, int outF32) {
  const int t = threadIdx.x;
  const int wave = t >> 6;
  const int lane = t & 63;
  const int quad = lane >> 4;
  const int m16 = lane & 15;
  const int sRow = t >> 2;  // staging: 4 threads x 8 elem per 32-elem row
  const int sOff = (t & 3) * 8;
  const int wr = (wave >> 1) * 64;
  const int wc = (wave & 1) * 64;

  const short* A0 = A + (size_t)(rowBase + sRow) * lda + sOff;
  const short* A1 = A0 + (size_t)64 * lda;
  const short* B0 = B + (size_t)(colBase + sRow) * ldb + sOff;
  const short* B1 = B0 + (size_t)64 * ldb;

  short* ldsA0 = As + wave * 512;  // wave-uniform bases (64 lanes * 16B)
  short* ldsA1 = As + 2048 + wave * 512;
  short* ldsB0 = Bs + wave * 512;
  short* ldsB1 = Bs + 2048 + wave * 512;

  f32x4 acc[4][4] = {};

  const int nK = K >> 5;
  for (int kt = 0; kt < nK; ++kt) {
    __syncthreads();
    const int ko = kt * 32;
    async_ld16(A0 + ko, ldsA0);
    async_ld16(A1 + ko, ldsA1);
    async_ld16(B0 + ko, ldsB0);
    async_ld16(B1 + ko, ldsB1);
    __syncthreads();

    short8 af[4], bfr[4];
#pragma unroll
    for (int i = 0; i < 4; ++i)
      af[i] = *(const short8*)(As + (wr + i * 16 + m16) * 32 + quad * 8);
#pragma unroll
    for (int i = 0; i < 4; ++i)
      bfr[i] = *(const short8*)(Bs + (wc + i * 16 + m16) * 32 + quad * 8);
#pragma unroll
    for (int i = 0; i < 4; ++i)
#pragma unroll
      for (int j = 0; j < 4; ++j)
        acc[i][j] = __builtin_amdgcn_mfma_f32_16x16x32_bf16(af[i], bfr[j],
                                                            acc[i][j], 0, 0, 0);
  }

  // epilogue: C/D layout col = lane&15, row = quad*4 + reg  [m89]
#pragma unroll
  for (int i = 0; i < 4; ++i)
#pragma unroll
    for (int j = 0; j < 4; ++j)
#pragma unroll
      for (int r = 0; r < 4; ++r) {
        const int row = rowBase + wr + i * 16 + quad * 4 + r;
        const int col = colBase + wc + j * 16 + m16;
        const size_t idx = (size_t)row * ldc + col;
        if (outF32)
          ((float*)C)[idx] = acc[i][j][r];
        else
          ((short*)C)[idx] = f2bs(acc[i][j][r]);
      }
}

__global__ __launch_bounds__(256) void qkv_gemm_kernel(
    const short* __restrict__ R, const short* __restrict__ WQ,
    const short* __restrict__ WK, const short* __restrict__ WV,
    short* __restrict__ q, short* __restrict__ k, short* __restrict__ v) {
  __shared__ __align__(16) short As[128 * 32];
  __shared__ __align__(16) short Bs[128 * 32];
  const int ct = blockIdx.x;  // 0..23: 16 Q tiles, 4 K tiles, 4 V tiles
  const int rowBase = blockIdx.y * 128;
  const short* B;
  short* C;
  int colBase, ldc;
  if (ct < 16) {
    B = WQ; C = q; colBase = ct * 128; ldc = 2048;
  } else if (ct < 20) {
    B = WK; C = k; colBase = (ct - 16) * 128; ldc = 512;
  } else {
    B = WV; C = v; colBase = (ct - 20) * 128; ldc = 512;
  }
  gemm128(R, 2048, B, 2048, C, ldc, rowBase, colBase, 2048, As, Bs, 0);
}

__global__ __launch_bounds__(256) void out_gemm_kernel(
    const short* __restrict__ A, const short* __restrict__ Bt,
    void* __restrict__ C, const int* __restrict__ flag) {
  __shared__ __align__(16) short As[128 * 32];
  __shared__ __align__(16) short Bs[128 * 32];
  const int outF32 = *flag;
  gemm128(A, 2048, Bt, 2048, C, 2048, blockIdx.y * 128, blockIdx.x * 128, 2048,
          As, Bs, outF32);
}

// ----------------------------------------------------------------------------
// W_O [2048,2048] -> W_O^T, flag-aware source dtype.
// ----------------------------------------------------------------------------
__global__ __launch_bounds__(256) void transpose_kernel(
    const void* __restrict__ in, short* __restrict__ out,
    const int* __restrict__ flag) {
  __shared__ short tile[64][65];
  const int bx = blockIdx.x, by = blockIdx.y;
  const int tx = threadIdx.x & 63, ty = threadIdx.x >> 6;
  const int isf = *flag;
#pragma unroll
  for (int i = 0; i < 16; ++i) {
    const int r = ty + i * 4;
    const size_t idx = (size_t)(by * 64 + r) * 2048 + bx * 64 + tx;
    tile[r][tx] = isf ? f2bs(((const float*)in)[idx]) : ((const short*)in)[idx];
  }
  __syncthreads();
#pragma unroll
  for (int i = 0; i < 16; ++i) {
    const int r = ty + i * 4;
    out[(size_t)(bx * 64 + r) * 2048 + by * 64 + tx] = tile[tx][r];
  }
}

// ----------------------------------------------------------------------------
// Causal flash attention. Grid (qt=32, head=32, b=2), 256 threads = 4 waves.
// Wave w owns q-rows w*16..w*16+15 of a 64-row block. 64-key K/V tiles in
// LDS; V transposed (VT[h][key]); 16B chunks XOR-swizzled by row so strided
// B-operand ds_read_b128s stay conflict-light. exp2-domain online softmax.
// ----------------------------------------------------------------------------
__global__ __launch_bounds__(256) void attn_kernel(
    const short* __restrict__ qbuf, const short* __restrict__ kbuf,
    const short* __restrict__ vbuf, short* __restrict__ obuf) {
  __shared__ __align__(16) short Ks[64 * 64];
  __shared__ __align__(16) short VT[64 * 64];
  __shared__ __align__(16) short Pb[4 * 16 * 64];

  const int qt = blockIdx.x;
  const int hd = blockIdx.y;
  const int b = blockIdx.z;
  const int kv = hd >> 2;  // repeat_interleave: q-head n -> kv-head n/4
  const int t = threadIdx.x;
  const int wave = t >> 6;
  const int lane = t & 63;
  const int quad = lane >> 4;
  const int col = lane & 15;

  // Q A-fragments: A[m=lane&15][k=quad*8+j], DH=64 in 2 chunks of 32
  const int qrow = qt * 64 + wave * 16 + col;
  const short* qp =
      qbuf + ((size_t)(b * 2048 + qrow)) * 2048 + hd * 64 + quad * 8;
  const short8 qf0 = *(const short8*)(qp);
  const short8 qf1 = *(const short8*)(qp + 32);

  float mloc[4], lloc[4];
  f32x4 oacc[4] = {};
#pragma unroll
  for (int r = 0; r < 4; ++r) {
    mloc[r] = -3.0e38f;  // finite: avoids any inf-inf path
    lloc[r] = 0.f;
  }

  const int sRow = t >> 3;  // K staging: 8 chunks/row, 32 rows per call
  const int sPos = t & 7;
  short* ksDst0 = Ks + wave * 512;
  short* ksDst1 = Ks + 2048 + wave * 512;
  short* P = Pb + wave * (16 * 64);

  const float SCALE = 0.125f * 1.44269504088896340736f;  // /sqrt(64) * log2e

  for (int kt = 0; kt <= qt; ++kt) {
    __syncthreads();
    // ---- stage K tile: lds chunk [row][pos] <- global chunk pos^(row&7)
    {
      const int r1 = sRow + 32;
      const short* kp0 = kbuf + ((size_t)(b * 2048 + kt * 64 + sRow)) * 512 +
                         kv * 64 + ((sPos ^ (sRow & 7)) * 8);
      const short* kp1 = kbuf + ((size_t)(b * 2048 + kt * 64 + r1)) * 512 +
                         kv * 64 + ((sPos ^ (r1 & 7)) * 8);
      async_ld16(kp0, ksDst0);
      async_ld16(kp1, ksDst1);
    }
    // ---- stage V transposed: VT[h][key], swizzled chunks, plain LDS writes
    {
      const int key = t >> 2;
      const int h0 = (t & 3) * 16;
      const short* vp =
          vbuf + ((size_t)(b * 2048 + kt * 64 + key)) * 512 + kv * 64 + h0;
      const short8 v0 = *(const short8*)(vp);
      const short8 v1 = *(const short8*)(vp + 8);
      const int klo = key & 7, khi = key >> 3;
#pragma unroll
      for (int j = 0; j < 8; ++j) {
        const int h = h0 + j;
        VT[h * 64 + ((khi ^ (h & 7)) * 8) + klo] = v0[j];
      }
#pragma unroll
      for (int j = 0; j < 8; ++j) {
        const int h = h0 + 8 + j;
        VT[h * 64 + ((khi ^ (h & 7)) * 8) + klo] = v1[j];
      }
    }
    __syncthreads();

    // ---- S = Q K^T : B[k=quad*8+j][n=col] = K[key=n][h=k]
    f32x4 s[4];
#pragma unroll
    for (int nt = 0; nt < 4; ++nt) {
      const int krow = nt * 16 + col;  // krow&7 == col&7
      const short8 kf0 =
          *(const short8*)(Ks + krow * 64 + ((quad ^ (col & 7)) * 8));
      const short8 kf1 =
          *(const short8*)(Ks + krow * 64 + (((4 + quad) ^ (col & 7)) * 8));
      f32x4 z = {0.f, 0.f, 0.f, 0.f};
      z = __builtin_amdgcn_mfma_f32_16x16x32_bf16(qf0, kf0, z, 0, 0, 0);
      z = __builtin_amdgcn_mfma_f32_16x16x32_bf16(qf1, kf1, z, 0, 0, 0);
      s[nt] = z;
    }

    // ---- scale + causal mask (diag tile only)
    const bool diag = (kt == qt);
#pragma unroll
    for (int nt = 0; nt < 4; ++nt)
#pragma unroll
      for (int r = 0; r < 4; ++r) {
        float x = s[nt][r] * SCALE;
        if (diag && (nt * 16 + col > wave * 16 + quad * 4 + r)) x = -1e30f;
        s[nt][r] = x;
      }

    // ---- online softmax: row max over 16 cols (xor-shfl within 16-group)
    float alpha[4], mnew[4];
#pragma unroll
    for (int r = 0; r < 4; ++r) {
      float mx = fmaxf(fmaxf(s[0][r], s[1][r]), fmaxf(s[2][r], s[3][r]));
#pragma unroll
      for (int off = 8; off >= 1; off >>= 1)
        mx = fmaxf(mx, __shfl_xor(mx, off, 64));
      const float mn = fmaxf(mloc[r], mx);
      alpha[r] = exp2f(mloc[r] - mn);
      mloc[r] = mn;
      mnew[r] = mn;
    }

    float rsum[4] = {0.f, 0.f, 0.f, 0.f};
#pragma unroll
    for (int nt = 0; nt < 4; ++nt)
#pragma unroll
      for (int r = 0; r < 4; ++r) {
        const float p = exp2f(s[nt][r] - mnew[r]);
        s[nt][r] = p;
        rsum[r] += p;
      }
#pragma unroll
    for (int r = 0; r < 4; ++r) {
#pragma unroll
      for (int off = 8; off >= 1; off >>= 1)
        rsum[r] += __shfl_xor(rsum[r], off, 64);
      lloc[r] = lloc[r] * alpha[r] + rsum[r];
    }
#pragma unroll
    for (int ct = 0; ct < 4; ++ct)
#pragma unroll
      for (int r = 0; r < 4; ++r) oacc[ct][r] *= alpha[r];

    // ---- P: C-layout -> LDS (bf16, swizzled) -> A-operand layout  [m120]
#pragma unroll
    for (int nt = 0; nt < 4; ++nt) {
      const int key = nt * 16 + col;
      const int khi = key >> 3, klo = key & 7;
#pragma unroll
      for (int r = 0; r < 4; ++r) {
        const int prow = quad * 4 + r;
        P[prow * 64 + ((khi ^ (prow & 7)) * 8) + klo] = f2bs(s[nt][r]);
      }
    }
    __syncthreads();  // P write -> P read; also orders Ks/VT reuse

    const short8 pf0 =
        *(const short8*)(P + col * 64 + ((quad ^ (col & 7)) * 8));
    const short8 pf1 =
        *(const short8*)(P + col * 64 + (((4 + quad) ^ (col & 7)) * 8));
#pragma unroll
    for (int ct = 0; ct < 4; ++ct) {
      const int vrow = ct * 16 + col;  // vrow&7 == col&7
      const short8 vf0 =
          *(const short8*)(VT + vrow * 64 + ((quad ^ (col & 7)) * 8));
      const short8 vf1 =
          *(const short8*)(VT + vrow * 64 + (((4 + quad) ^ (col & 7)) * 8));
      oacc[ct] =
          __builtin_amdgcn_mfma_f32_16x16x32_bf16(pf0, vf0, oacc[ct], 0, 0, 0);
      oacc[ct] =
          __builtin_amdgcn_mfma_f32_16x16x32_bf16(pf1, vf1, oacc[ct], 0, 0, 0);
    }
  }

  // ---- epilogue: O /= l, write attn_out[b, q, head*64+h] (always bf16)
  float inv[4];
#pragma unroll
  for (int r = 0; r < 4; ++r) inv[r] = 1.0f / lloc[r];
#pragma unroll
  for (int ct = 0; ct < 4; ++ct)
#pragma unroll
    for (int r = 0; r < 4; ++r) {
      const int row = qt * 64 + wave * 16 + quad * 4 + r;
      obuf[((size_t)(b * 2048 + row)) * 2048 + hd * 64 + ct * 16 + col] =
          f2bs(oacc[ct][r] * inv[r]);
    }
}

// ----------------------------------------------------------------------------
extern "C" void kernel_launch(void* const* d_in, const int* in_sizes, int n_in,
                              void* d_out, int out_size, void* d_ws,
                              size_t ws_size, hipStream_t stream) {
  char* ws = (char*)d_ws;
  int* flag = (int*)ws;                       // [0,256): dtype flag
  short* rbuf = (short*)(ws + 256);           // 16.78 MB [4096,2048]
  short* wqb = rbuf + 8388608;                //  8.39 MB [2048,2048]
  short* wkb = wqb + 4194304;                 //  2.10 MB [512,2048]
  short* wvb = wkb + 1048576;                 //  2.10 MB [512,2048]
  short* kbuf = wvb + 1048576;                //  4.19 MB [4096,512]
  short* vbuf = kbuf + 2097152;               //  4.19 MB [4096,512]
  short* abuf = vbuf + 2097152;               // 16.78 MB [4096,2048]
  short* wot = abuf + 8388608;                //  8.39 MB [2048,2048]
  short* qbuf = (short*)d_out;                // d_out >= 16.78 MB: q scratch

  hipLaunchKernelGGL(detect_kernel, dim3(1), dim3(256), 0, stream,
                     (const short*)d_in[0], flag);
  hipLaunchKernelGGL(convert_kernel, dim3(7168), dim3(256), 0, stream,
                     d_in[0], d_in[1], d_in[2], d_in[3], rbuf, wqb, wkb, wvb,
                     flag);
  hipLaunchKernelGGL(qkv_gemm_kernel, dim3(24, 32), dim3(256), 0, stream,
                     rbuf, wqb, wkb, wvb, qbuf, kbuf, vbuf);
  hipLaunchKernelGGL(attn_kernel, dim3(32, 32, 2), dim3(256), 0, stream,
                     qbuf, kbuf, vbuf, abuf);
  hipLaunchKernelGGL(transpose_kernel, dim3(32, 32), dim3(256), 0, stream,
                     d_in[4], wot, flag);
  hipLaunchKernelGGL(out_gemm_kernel, dim3(16, 32), dim3(256), 0, stream,
                     abuf, wot, (void*)d_out, flag);
}

// Round 3
// 405.417 us; speedup vs baseline: 1.2666x; 1.2666x over previous
//
#include <hip/hip_runtime.h>

// ============================================================================
// Attention_14362370637857 on MI355X (gfx950).
// B=2, S=2048, D_MODEL=2048, NH=32, NKV=8 (GQA rep=4), DH=64.
//
// Pipeline:
//   1) detect_kernel   : dtype sniff (bf16 vs f32 inputs) -> flag
//   2) convert_kernel  : residual,W_Q,W_K,W_V -> canonical bf16 in ws
//   3) qkv_gemm_kernel : R[4096,2048] x W^T -> q (in d_out), k, v
//   4) vt_kernel       : v [b,p,h] -> vT [b,h,p]  (aliases spent wqb region)
//   5) attn_kernel     : causal flash attention (S^T orientation) -> abuf
//   6) transpose_kernel: W_O -> W_O^T (flag-aware read)
//   7) out_gemm_kernel : abuf x W_O^T -> d_out (bf16 or f32 per flag)
//
// attn v2: q-tile 128 (4 waves x 32 rows), S^T = K*Q^T so softmax reductions
// are 2 shfls, double-buffered async K/VT staging (1 barrier/iter), wave-local
// P transit (ds_write_b64 + ds_read_b128, lgkmcnt-only ordering).
// ============================================================================

typedef __attribute__((ext_vector_type(8))) short short8;   // 8 bf16
typedef __attribute__((ext_vector_type(4))) short short4v;  // 4 bf16 = 8B
typedef __attribute__((ext_vector_type(4))) float f32x4;    // MFMA 16x16 C/D

__device__ __forceinline__ short f2bs(float f) {  // f32 -> bf16 bits, RNE
  unsigned u = __float_as_uint(f);
  u = (u + 0x7fffu + ((u >> 16) & 1u)) >> 16;
  return (short)u;
}
__device__ __forceinline__ float bs2f(short s) {  // bf16 bits -> f32
  return __uint_as_float(((unsigned)(unsigned short)s) << 16);
}

__device__ __forceinline__ void async_ld16(const void* g, void* l) {
  __builtin_amdgcn_global_load_lds((__attribute__((address_space(1))) void*)(g),
                                   (__attribute__((address_space(3))) void*)(l),
                                   16, 0, 0);
}

// ----------------------------------------------------------------------------
__global__ __launch_bounds__(256) void detect_kernel(const short* __restrict__ r,
                                                     int* __restrict__ flag) {
  __shared__ int bad;
  if (threadIdx.x == 0) bad = 0;
  __syncthreads();
  int mybad = 0;
#pragma unroll
  for (int i = 0; i < 16; ++i) {
    float x = bs2f(r[threadIdx.x + i * 256]);
    if (!(fabsf(x) < 100.0f)) mybad = 1;
  }
  if (mybad) atomicOr(&bad, 1);
  __syncthreads();
  if (threadIdx.x == 0) *flag = bad;
}

// ----------------------------------------------------------------------------
__global__ __launch_bounds__(256) void convert_kernel(
    const void* __restrict__ s0, const void* __restrict__ s1,
    const void* __restrict__ s2, const void* __restrict__ s3,
    short* __restrict__ d0, short* __restrict__ d1, short* __restrict__ d2,
    short* __restrict__ d3, const int* __restrict__ flag) {
  long off = (long)blockIdx.x * 256 + threadIdx.x;
  const void* src;
  short* dst;
  if (off < 1048576) {
    src = s0; dst = d0;
  } else if ((off -= 1048576) < 524288) {
    src = s1; dst = d1;
  } else if ((off -= 524288) < 131072) {
    src = s2; dst = d2;
  } else {
    off -= 131072; src = s3; dst = d3;
  }
  const long e = off * 8;
  short8 v;
  if (*flag) {
    const float* f = (const float*)src + e;
    const f32x4 a = *(const f32x4*)(f);
    const f32x4 b = *(const f32x4*)(f + 4);
#pragma unroll
    for (int j = 0; j < 4; ++j) {
      v[j] = f2bs(a[j]);
      v[4 + j] = f2bs(b[j]);
    }
  } else {
    v = *(const short8*)((const short*)src + e);
  }
  *(short8*)(dst + e) = v;
}

// ----------------------------------------------------------------------------
// C[M,N] = A[M,K] * B[N,K]^T (row-major bf16), 128x128 tile, BK=32.
// ----------------------------------------------------------------------------
__device__ __forceinline__ void gemm128(const short* __restrict__ A, int lda,
                                        const short* __restrict__ B, int ldb,
                                        void* __restrict__ C, int ldc,
                                        int rowBase, int colBase, int K,
                                        short* As, short* Bs, int outF32) {
  const int t = threadIdx.x;
  const int wave = t >> 6;
  const int lane = t & 63;
  const int quad = lane >> 4;
  const int m16 = lane & 15;
  const int sRow = t >> 2;
  const int sOff = (t & 3) * 8;
  const int wr = (wave >> 1) * 64;
  const int wc = (wave & 1) * 64;

  const short* A0 = A + (size_t)(rowBase + sRow) * lda + sOff;
  const short* A1 = A0 + (size_t)64 * lda;
  const short* B0 = B + (size_t)(colBase + sRow) * ldb + sOff;
  const short* B1 = B0 + (size_t)64 * ldb;

  short* ldsA0 = As + wave * 512;
  short* ldsA1 = As + 2048 + wave * 512;
  short* ldsB0 = Bs + wave * 512;
  short* ldsB1 = Bs + 2048 + wave * 512;

  f32x4 acc[4][4] = {};

  const int nK = K >> 5;
  for (int kt = 0; kt < nK; ++kt) {
    __syncthreads();
    const int ko = kt * 32;
    async_ld16(A0 + ko, ldsA0);
    async_ld16(A1 + ko, ldsA1);
    async_ld16(B0 + ko, ldsB0);
    async_ld16(B1 + ko, ldsB1);
    __syncthreads();

    short8 af[4], bfr[4];
#pragma unroll
    for (int i = 0; i < 4; ++i)
      af[i] = *(const short8*)(As + (wr + i * 16 + m16) * 32 + quad * 8);
#pragma unroll
    for (int i = 0; i < 4; ++i)
      bfr[i] = *(const short8*)(Bs + (wc + i * 16 + m16) * 32 + quad * 8);
#pragma unroll
    for (int i = 0; i < 4; ++i)
#pragma unroll
      for (int j = 0; j < 4; ++j)
        acc[i][j] = __builtin_amdgcn_mfma_f32_16x16x32_bf16(af[i], bfr[j],
                                                            acc[i][j], 0, 0, 0);
  }

#pragma unroll
  for (int i = 0; i < 4; ++i)
#pragma unroll
    for (int j = 0; j < 4; ++j)
#pragma unroll
      for (int r = 0; r < 4; ++r) {
        const int row = rowBase + wr + i * 16 + quad * 4 + r;
        const int col = colBase + wc + j * 16 + m16;
        const size_t idx = (size_t)row * ldc + col;
        if (outF32)
          ((float*)C)[idx] = acc[i][j][r];
        else
          ((short*)C)[idx] = f2bs(acc[i][j][r]);
      }
}

__global__ __launch_bounds__(256) void qkv_gemm_kernel(
    const short* __restrict__ R, const short* __restrict__ WQ,
    const short* __restrict__ WK, const short* __restrict__ WV,
    short* __restrict__ q, short* __restrict__ k, short* __restrict__ v) {
  __shared__ __align__(16) short As[128 * 32];
  __shared__ __align__(16) short Bs[128 * 32];
  const int ct = blockIdx.x;
  const int rowBase = blockIdx.y * 128;
  const short* B;
  short* C;
  int colBase, ldc;
  if (ct < 16) {
    B = WQ; C = q; colBase = ct * 128; ldc = 2048;
  } else if (ct < 20) {
    B = WK; C = k; colBase = (ct - 16) * 128; ldc = 512;
  } else {
    B = WV; C = v; colBase = (ct - 20) * 128; ldc = 512;
  }
  gemm128(R, 2048, B, 2048, C, ldc, rowBase, colBase, 2048, As, Bs, 0);
}

__global__ __launch_bounds__(256) void out_gemm_kernel(
    const short* __restrict__ A, const short* __restrict__ Bt,
    void* __restrict__ C, const int* __restrict__ flag) {
  __shared__ __align__(16) short As[128 * 32];
  __shared__ __align__(16) short Bs[128 * 32];
  const int outF32 = *flag;
  gemm128(A, 2048, Bt, 2048, C, 2048, blockIdx.y * 128, blockIdx.x * 128, 2048,
          As, Bs, outF32);
}

// ----------------------------------------------------------------------------
// W_O [2048,2048] -> W_O^T, flag-aware source dtype.
// ----------------------------------------------------------------------------
__global__ __launch_bounds__(256) void transpose_kernel(
    const void* __restrict__ in, short* __restrict__ out,
    const int* __restrict__ flag) {
  __shared__ short tile[64][65];
  const int bx = blockIdx.x, by = blockIdx.y;
  const int tx = threadIdx.x & 63, ty = threadIdx.x >> 6;
  const int isf = *flag;
#pragma unroll
  for (int i = 0; i < 16; ++i) {
    const int r = ty + i * 4;
    const size_t idx = (size_t)(by * 64 + r) * 2048 + bx * 64 + tx;
    tile[r][tx] = isf ? f2bs(((const float*)in)[idx]) : ((const short*)in)[idx];
  }
  __syncthreads();
#pragma unroll
  for (int i = 0; i < 16; ++i) {
    const int r = ty + i * 4;
    out[(size_t)(bx * 64 + r) * 2048 + by * 64 + tx] = tile[tx][r];
  }
}

// ----------------------------------------------------------------------------
// v [2,2048,512] -> vT [2,512,2048]
// ----------------------------------------------------------------------------
__global__ __launch_bounds__(256) void vt_kernel(const short* __restrict__ v,
                                                 short* __restrict__ vt) {
  __shared__ short tile[64][65];
  const int hb = blockIdx.x * 64, pb = blockIdx.y * 64, b = blockIdx.z;
  const int tx = threadIdx.x & 63, ty = threadIdx.x >> 6;
#pragma unroll
  for (int i = 0; i < 16; ++i) {
    const int r = ty + i * 4;
    tile[r][tx] = v[((size_t)(b * 2048 + pb + r)) * 512 + hb + tx];
  }
  __syncthreads();
#pragma unroll
  for (int i = 0; i < 16; ++i) {
    const int r = ty + i * 4;
    vt[((size_t)(b * 512 + hb + r)) * 2048 + pb + tx] = tile[tx][r];
  }
}

// ----------------------------------------------------------------------------
// Causal flash attention, S^T orientation. Grid (16,32,2), 4 waves.
// Wave w owns q-rows [qbase+32w, qbase+32w+32). Per 64-key tile:
//   S^T[key][qrow] = K-tile(A) x Q^T(B);  O^T[h][qrow] += V^T(A) x P^T(B).
// K/VT double-buffered via async_ld16 (8-short chunk XOR swizzle by row&7);
// P per-wave in LDS (4-short chunk XOR swizzle by qrow&3).
// ----------------------------------------------------------------------------
__global__ __launch_bounds__(256, 3) void attn_kernel(
    const short* __restrict__ qbuf, const short* __restrict__ kbuf,
    const short* __restrict__ vtb, short* __restrict__ obuf) {
  __shared__ __align__(16) short Ks[2][64 * 64];
  __shared__ __align__(16) short VT[2][64 * 64];
  __shared__ __align__(16) short Pb[4][32 * 64];

  const int QT = blockIdx.x;  // 0..15
  const int hd = blockIdx.y;
  const int b = blockIdx.z;
  const int kv = hd >> 2;
  const int t = threadIdx.x;
  const int wave = t >> 6;
  const int lane = t & 63;
  const int quad = lane >> 4;
  const int col = lane & 15;
  const int qbase = QT * 128;
  const int rb0 = qbase + wave * 32;

  // Q B-frags: B[k=quad*8+j (+32*kh)][n=col] = Q[qrow][h]
  short8 qf[2][2];
#pragma unroll
  for (int nt = 0; nt < 2; ++nt) {
    const int qr = rb0 + nt * 16 + col;
    const short* qp = qbuf + ((size_t)(b * 2048 + qr)) * 2048 + hd * 64 + quad * 8;
    qf[nt][0] = *(const short8*)(qp);
    qf[nt][1] = *(const short8*)(qp + 32);
  }

  float mloc[2] = {-3.0e38f, -3.0e38f};
  float lloc[2] = {0.f, 0.f};
  f32x4 oacc[2][4] = {};

  // staging: thread t covers rows t>>3 and (t>>3)+32, chunk t&7 (swizzled)
  const int sRow = t >> 3;
  const int sPos = t & 7;
  const int r1 = sRow + 32;
  const short* kRow0 = kbuf + ((size_t)(b * 2048 + sRow)) * 512 + kv * 64 +
                       ((sPos ^ (sRow & 7)) * 8);
  const short* kRow1 = kbuf + ((size_t)(b * 2048 + r1)) * 512 + kv * 64 +
                       ((sPos ^ (r1 & 7)) * 8);
  const short* vRow0 = vtb + ((size_t)(b * 512 + kv * 64 + sRow)) * 2048 +
                       ((sPos ^ (sRow & 7)) * 8);
  const short* vRow1 = vtb + ((size_t)(b * 512 + kv * 64 + r1)) * 2048 +
                       ((sPos ^ (r1 & 7)) * 8);
  short* P = &Pb[wave][0];
  const int swz = 4 * (col & 3);  // P chunk swizzle

  const float SCALE = 0.125f * 1.44269504088896340736f;  // /sqrt(64) * log2e
  const int nkt = 2 * QT + 2;

  // prologue: stage tile 0 into buffer 0
  {
    async_ld16(kRow0, &Ks[0][wave * 512]);
    async_ld16(kRow1, &Ks[0][2048 + wave * 512]);
    async_ld16(vRow0, &VT[0][wave * 512]);
    async_ld16(vRow1, &VT[0][2048 + wave * 512]);
  }

  for (int kt = 0; kt < nkt; ++kt) {
    __syncthreads();  // drains vmcnt: tile kt resident in buf kt&1
    if (kt + 1 < nkt) {
      const int nb = (kt + 1) & 1;
      const size_t ko = (size_t)(kt + 1) * 64 * 512;
      const int vo = (kt + 1) * 64;
      async_ld16(kRow0 + ko, &Ks[nb][wave * 512]);
      async_ld16(kRow1 + ko, &Ks[nb][2048 + wave * 512]);
      async_ld16(vRow0 + vo, &VT[nb][wave * 512]);
      async_ld16(vRow1 + vo, &VT[nb][2048 + wave * 512]);
    }
    const int ktb = kt * 64;
    if (ktb > rb0 + 31) continue;  // wave fully above diagonal: skip compute
    const short* ks = &Ks[kt & 1][0];
    const short* vs = &VT[kt & 1][0];

    // K A-frags: A[m=col (+16mt)][k=quad*8+j (+32kh)] = K[key][h]
    short8 kf[4][2];
#pragma unroll
    for (int mt = 0; mt < 4; ++mt) {
      const int row = mt * 16 + col;
      kf[mt][0] = *(const short8*)(ks + row * 64 + ((quad ^ (col & 7)) * 8));
      kf[mt][1] = *(const short8*)(ks + row * 64 + (((4 + quad) ^ (col & 7)) * 8));
    }

#pragma unroll
    for (int nt = 0; nt < 2; ++nt) {
      const int rb = rb0 + nt * 16;
      if (ktb > rb + 15) continue;  // n-tile fully masked

      f32x4 st[4];
#pragma unroll
      for (int mt = 0; mt < 4; ++mt) {
        f32x4 z = {0.f, 0.f, 0.f, 0.f};
        z = __builtin_amdgcn_mfma_f32_16x16x32_bf16(kf[mt][0], qf[nt][0], z, 0, 0, 0);
        z = __builtin_amdgcn_mfma_f32_16x16x32_bf16(kf[mt][1], qf[nt][1], z, 0, 0, 0);
        st[mt] = z;
      }

      if (ktb + 63 > rb) {  // diagonal overlap: per-score causal mask
        const int qrow = rb + col;
#pragma unroll
        for (int mt = 0; mt < 4; ++mt)
#pragma unroll
          for (int r = 0; r < 4; ++r)
            if (ktb + mt * 16 + quad * 4 + r > qrow) st[mt][r] = -1.0e30f;
      }

      // row max: 15 in-lane + 2 shfl (raw domain)
      float mx = st[0][0];
#pragma unroll
      for (int mt = 0; mt < 4; ++mt)
#pragma unroll
        for (int r = 0; r < 4; ++r) mx = fmaxf(mx, st[mt][r]);
      mx = fmaxf(mx, __shfl_xor(mx, 16, 64));
      mx = fmaxf(mx, __shfl_xor(mx, 32, 64));

      const float mn = fmaxf(mloc[nt], mx);
      const float alpha = exp2f((mloc[nt] - mn) * SCALE);
      mloc[nt] = mn;
      const float c = mn * SCALE;

      float rs = 0.f;
#pragma unroll
      for (int mt = 0; mt < 4; ++mt)
#pragma unroll
        for (int r = 0; r < 4; ++r) {
          const float p = exp2f(st[mt][r] * SCALE - c);
          st[mt][r] = p;
          rs += p;
        }
      rs += __shfl_xor(rs, 16, 64);
      rs += __shfl_xor(rs, 32, 64);
      lloc[nt] = lloc[nt] * alpha + rs;
#pragma unroll
      for (int ct = 0; ct < 4; ++ct)
#pragma unroll
        for (int r = 0; r < 4; ++r) oacc[nt][ct][r] *= alpha;

      // P write: keys mt*16+quad*4+{0..3} contiguous -> b64, chunk-swizzled
#pragma unroll
      for (int mt = 0; mt < 4; ++mt) {
        short4v w;
#pragma unroll
        for (int r = 0; r < 4; ++r) w[r] = f2bs(st[mt][r]);
        *(short4v*)(P + (nt * 16 + col) * 64 + (quad + 4 * (mt ^ (col & 3))) * 4) = w;
      }
    }

    asm volatile("s_waitcnt lgkmcnt(0)" ::: "memory");  // P visible wave-wide

    // P^T B-frags: B[k=key=quad*8+j (+32kh)][n=col]
    short8 pf[2][2];
#pragma unroll
    for (int nt = 0; nt < 2; ++nt) {
      if (ktb > rb0 + nt * 16 + 15) continue;
      const int base = (nt * 16 + col) * 64;
      pf[nt][0] = *(const short8*)(P + base + ((2 * quad) ^ swz) * 4);
      pf[nt][1] = *(const short8*)(P + base + ((8 + 2 * quad) ^ swz) * 4);
    }

    // V^T A-frags + PV accumulate
#pragma unroll
    for (int ct = 0; ct < 4; ++ct) {
      const int h = ct * 16 + col;
      const short8 va = *(const short8*)(vs + h * 64 + ((quad ^ (col & 7)) * 8));
      const short8 vb = *(const short8*)(vs + h * 64 + (((4 + quad) ^ (col & 7)) * 8));
#pragma unroll
      for (int nt = 0; nt < 2; ++nt) {
        if (ktb > rb0 + nt * 16 + 15) continue;
        oacc[nt][ct] =
            __builtin_amdgcn_mfma_f32_16x16x32_bf16(va, pf[nt][0], oacc[nt][ct], 0, 0, 0);
        oacc[nt][ct] =
            __builtin_amdgcn_mfma_f32_16x16x32_bf16(vb, pf[nt][1], oacc[nt][ct], 0, 0, 0);
      }
    }
  }

  // epilogue: O^T[h][qrow] / l -> obuf[b,qrow,hd*64+h]; 4 consecutive h -> 8B
#pragma unroll
  for (int nt = 0; nt < 2; ++nt) {
    const float inv = 1.0f / lloc[nt];
    const int qrow = rb0 + nt * 16 + col;
    short* orow = obuf + ((size_t)(b * 2048 + qrow)) * 2048 + hd * 64;
#pragma unroll
    for (int ct = 0; ct < 4; ++ct) {
      short4v w;
#pragma unroll
      for (int r = 0; r < 4; ++r) w[r] = f2bs(oacc[nt][ct][r] * inv);
      *(short4v*)(orow + ct * 16 + quad * 4) = w;
    }
  }
}

// ----------------------------------------------------------------------------
extern "C" void kernel_launch(void* const* d_in, const int* in_sizes, int n_in,
                              void* d_out, int out_size, void* d_ws,
                              size_t ws_size, hipStream_t stream) {
  char* ws = (char*)d_ws;
  int* flag = (int*)ws;              // [0,256): dtype flag
  short* rbuf = (short*)(ws + 256);  // [4096,2048] bf16
  short* wqb = rbuf + 8388608;       // [2048,2048]
  short* wkb = wqb + 4194304;        // [512,2048]
  short* wvb = wkb + 1048576;        // [512,2048]
  short* kbuf = wvb + 1048576;       // [4096,512]
  short* vbuf = kbuf + 2097152;      // [4096,512]
  short* abuf = vbuf + 2097152;      // [4096,2048]
  short* wot = abuf + 8388608;       // [2048,2048]
  short* vtb = wqb;                  // [2,512,2048] aliases spent W_Q copy
  short* qbuf = (short*)d_out;       // q scratch lives in d_out

  hipLaunchKernelGGL(detect_kernel, dim3(1), dim3(256), 0, stream,
                     (const short*)d_in[0], flag);
  hipLaunchKernelGGL(convert_kernel, dim3(7168), dim3(256), 0, stream,
                     d_in[0], d_in[1], d_in[2], d_in[3], rbuf, wqb, wkb, wvb,
                     flag);
  hipLaunchKernelGGL(qkv_gemm_kernel, dim3(24, 32), dim3(256), 0, stream,
                     rbuf, wqb, wkb, wvb, qbuf, kbuf, vbuf);
  hipLaunchKernelGGL(vt_kernel, dim3(8, 32, 2), dim3(256), 0, stream,
                     vbuf, vtb);
  hipLaunchKernelGGL(attn_kernel, dim3(16, 32, 2), dim3(256), 0, stream,
                     qbuf, kbuf, vtb, abuf);
  hipLaunchKernelGGL(transpose_kernel, dim3(32, 32), dim3(256), 0, stream,
                     d_in[4], wot, flag);
  hipLaunchKernelGGL(out_gemm_kernel, dim3(16, 32), dim3(256), 0, stream,
                     abuf, wot, (void*)d_out, flag);
}